// Round 8
// baseline (391.875 us; speedup 1.0000x reference)
//
#include <hip/hip_runtime.h>
#include <hip/hip_bf16.h>

using bf16 = __hip_bfloat16;
typedef __attribute__((ext_vector_type(8))) __bf16 bf16x8;
typedef __attribute__((ext_vector_type(4))) float f32x4;

static constexpr int T = 4096, DIM = 768, H = 6, D = 128, N3 = 2304;
static constexpr int PPH = 280;                    // stored partials per head (qt>=8)
static constexpr float kEps = 1.1920929e-07f;
static constexpr float kC1 = 0.12f * 1.44269504f;  // kScale * log2(e)
static constexpr float kTHR = 66.6f;               // raw-domain defer threshold (~e^8 P bound)

__device__ __forceinline__ void gll16(const bf16* g, bf16* l) {
  __builtin_amdgcn_global_load_lds((const __attribute__((address_space(1))) void*)g,
                                   (__attribute__((address_space(3))) void*)l, 16, 0, 0);
}

// sum_{q'<qt} ((q'>>3)+1)
__device__ __forceinline__ int pre_qt(int qt) {
  const int k = qt >> 3, rr = qt & 7;
  return qt + 4 * k * (k - 1) + rr * k;
}

// fused fp32->bf16 converts (x, qkv_w, cproj) + rotary table build
__global__ __launch_bounds__(256) void prep(const float* __restrict__ x,
                                            const float* __restrict__ qkv_w,
                                            const float* __restrict__ cproj,
                                            bf16* __restrict__ xb, bf16* __restrict__ wb,
                                            bf16* __restrict__ cb, float2* __restrict__ tab) {
  const int NBX = T * DIM / 2048, NBW = N3 * DIM / 2048, NBC = DIM * DIM / 2048;
  int b = blockIdx.x;
  const int tid = threadIdx.x;
  if (b < NBX + NBW + NBC) {
    const float* in;
    bf16* out;
    if (b < NBX) { in = x; out = xb; }
    else if (b < NBX + NBW) { in = qkv_w; out = wb; b -= NBX; }
    else { in = cproj; out = cb; b -= NBX + NBW; }
    const int i = (b * 256 + tid) * 8;
    const float4 a = *(const float4*)(in + i);
    const float4 c = *(const float4*)(in + i + 4);
    bf16 t[8] = {(bf16)a.x, (bf16)a.y, (bf16)a.z, (bf16)a.w,
                 (bf16)c.x, (bf16)c.y, (bf16)c.z, (bf16)c.w};
    *(int4*)(out + i) = *(const int4*)t;
  } else {
    b -= NBX + NBW + NBC;
    const int i = b * 256 + tid;  // T*32 total
    const int t = i >> 5, j = i & 31;
    const float af = exp2f(-10.f * (float)j * (1.f / 31.f));
    float s, c;
    sincosf((float)t * af, &s, &c);
    tab[i] = make_float2(c, s);
  }
}

// C(MxN) = A(MxK) * B(NxK)^T, A/B row-major bf16, C row-major CT.
template <typename CT>
__global__ __launch_bounds__(256) void gemm_bt(const bf16* __restrict__ A,
                                               const bf16* __restrict__ B,
                                               CT* __restrict__ C,
                                               int M, int N, int K) {
  __shared__ bf16 lA[128][64];
  __shared__ bf16 lB[128][64];
  const int tid = threadIdx.x, lane = tid & 63, wid = tid >> 6;
  const int brow = blockIdx.y * 128, bcol = blockIdx.x * 128;
  const int wm = (wid >> 1) * 64, wn = (wid & 1) * 64;
  const int r = lane & 15, g = lane >> 4;
  f32x4 acc[4][4] = {};
  const int srow = wid * 32 + (lane >> 3);
  const int scol = (lane & 7) * 8;
  const bf16* gA = A + (long)(brow + srow) * K + scol;
  const bf16* gB = B + (long)(bcol + srow) * K + scol;
  for (int k0 = 0; k0 < K; k0 += 64) {
    __syncthreads();
#pragma unroll
    for (int i = 0; i < 4; ++i) {
      gll16(gA + (long)i * 8 * K + k0, &lA[wid * 32 + i * 8][0]);
      gll16(gB + (long)i * 8 * K + k0, &lB[wid * 32 + i * 8][0]);
    }
    __syncthreads();
#pragma unroll
    for (int kk = 0; kk < 2; ++kk) {
      bf16x8 af[4], bfr[4];
#pragma unroll
      for (int m = 0; m < 4; ++m)
        af[m] = *(const bf16x8*)&lA[wm + m * 16 + r][kk * 32 + g * 8];
#pragma unroll
      for (int n = 0; n < 4; ++n)
        bfr[n] = *(const bf16x8*)&lB[wn + n * 16 + r][kk * 32 + g * 8];
#pragma unroll
      for (int m = 0; m < 4; ++m)
#pragma unroll
        for (int n = 0; n < 4; ++n)
          acc[m][n] = __builtin_amdgcn_mfma_f32_16x16x32_bf16(af[m], bfr[n], acc[m][n], 0, 0, 0);
    }
  }
  const int crow = brow + wm + g * 4;
  const int ccol = bcol + wn + r;
#pragma unroll
  for (int m = 0; m < 4; ++m)
#pragma unroll
    for (int n = 0; n < 4; ++n)
#pragma unroll
      for (int q = 0; q < 4; ++q)
        C[(long)(crow + m * 16 + q) * N + ccol + n * 16] = (CT)acc[m][n][q];
}

// RMS-norm + rotary for q,k only (table-driven). One wave per (t,h). Writes (h,t,d).
__global__ __launch_bounds__(256) void qkv_post(const bf16* __restrict__ qkv,
                                                const float2* __restrict__ tab,
                                                bf16* __restrict__ qb,
                                                bf16* __restrict__ kb) {
  const int idx = blockIdx.x * 4 + (threadIdx.x >> 6);
  const int lane = threadIdx.x & 63;
  const int t = idx / H, h = idx % H;
  const bf16* row = qkv + (long)t * N3 + h * D;
  float q1 = __bfloat162float(row[lane]);
  float q2 = __bfloat162float(row[lane + 64]);
  float k1 = __bfloat162float(row[768 + lane]);
  float k2 = __bfloat162float(row[768 + lane + 64]);
  float qs = q1 * q1 + q2 * q2, ks = k1 * k1 + k2 * k2;
#pragma unroll
  for (int off = 32; off; off >>= 1) {
    qs += __shfl_xor(qs, off);
    ks += __shfl_xor(ks, off);
  }
  const float qsc = rsqrtf(qs * (1.f / 128.f) + kEps);
  const float ksc = rsqrtf(ks * (1.f / 128.f) + kEps);
  q1 *= qsc; q2 *= qsc; k1 *= ksc; k2 *= ksc;
  float c = 1.f, s = 0.f;
  if (lane < 32) {
    const float2 cs = tab[t * 32 + lane];
    c = cs.x; s = cs.y;
  }
  const float nq1 = q1 * c + q2 * s, nq2 = q2 * c - q1 * s;
  const float nk1 = k1 * c + k2 * s, nk2 = k2 * c - k1 * s;
  bf16* qo = qb + ((long)h * T + t) * D;
  bf16* ko = kb + ((long)h * T + t) * D;
  qo[lane] = (bf16)nq1; qo[lane + 64] = (bf16)nq2;
  ko[lane] = (bf16)nk1; ko[lane + 64] = (bf16)nk2;
}

// v = l0*v + l1*ve, transposed to (h, d, t) with coalesced 64B stores.
__global__ __launch_bounds__(256) void v_trans(const bf16* __restrict__ qkv,
                                               const float* __restrict__ ve,
                                               const float* __restrict__ lam,
                                               bf16* __restrict__ vt) {
  __shared__ bf16 tile[64][129];
  const int t0 = blockIdx.x * 64, h = blockIdx.y;
  const int tid = threadIdx.x;
  const float l0 = lam[0], l1 = lam[1];
  const int row = tid >> 2;
  const int seg = (tid & 3) * 32;
  const bf16* src = qkv + (long)(t0 + row) * N3 + 1536 + h * D + seg;
  const float* vs = ve + (long)(t0 + row) * DIM + h * D + seg;
#pragma unroll
  for (int j = 0; j < 32; j += 8) {
    bf16x8 a = *(const bf16x8*)(src + j);
    const float4 e0 = *(const float4*)(vs + j);
    const float4 e1 = *(const float4*)(vs + j + 4);
    const float ef[8] = {e0.x, e0.y, e0.z, e0.w, e1.x, e1.y, e1.z, e1.w};
#pragma unroll
    for (int u = 0; u < 8; ++u)
      tile[row][seg + j + u] = (bf16)(l0 * (float)a[u] + l1 * ef[u]);
  }
  __syncthreads();
  const int d = tid >> 1, half = tid & 1;
  bf16 outr[32];
#pragma unroll
  for (int j = 0; j < 32; ++j) outr[j] = tile[half * 32 + j][d];
  bf16* dst = vt + ((long)h * D + d) * T + t0 + half * 32;
#pragma unroll
  for (int c = 0; c < 4; ++c)
    *(int4*)(dst + c * 8) = *(const int4*)&outr[c * 8];
}

// Flash-style causal attention. Block = 128-row q-supertile (2 q-tiles A/B) x
// 8-KV-tile chunk. Shared kf/vf LDS reads feed both q-tiles (halves LDS traffic).
// 48KB LDS, 3 blocks/CU. Single-chunk supertiles (s<4) write yb directly.
__global__ __launch_bounds__(256, 3) void attn(const bf16* __restrict__ qb,
                                               const bf16* __restrict__ kb,
                                               const bf16* __restrict__ vt,
                                               bf16* __restrict__ po,
                                               float* __restrict__ pm,
                                               float* __restrict__ ps,
                                               bf16* __restrict__ yb) {
  __shared__ bf16 Kl[64][128];
  __shared__ bf16 Vl[128][64];
  __shared__ bf16 Pl[4][2][16][64];
  const int bid = blockIdx.x;
  const int h = bid % H;
  const int fi = bid / H;
  int s = 31, ci = 0, acc0 = 0;          // heavy-first band decode
  for (int ss = 31; ss >= 0; --ss) {
    const int n = (ss >> 2) + 1;
    if (fi < acc0 + n) { s = ss; ci = fi - acc0; break; }
    acc0 += n;
  }
  const int qtA = 2 * s, qtB = 2 * s + 1;
  const int ts = ci * 8;
  const int te = min(ts + 8, 2 * s + 2);
  const int tid = threadIdx.x, lane = tid & 63, w = tid >> 6;
  const int r = lane & 15, g = lane >> 4;

  bf16x8 qfA[4], qfB[4];
#pragma unroll
  for (int kk = 0; kk < 4; ++kk) {
    qfA[kk] = *(const bf16x8*)(qb + ((long)h * T + qtA * 64 + w * 16 + r) * D + kk * 32 + g * 8);
    qfB[kk] = *(const bf16x8*)(qb + ((long)h * T + qtB * 64 + w * 16 + r) * D + kk * 32 + g * 8);
  }
  f32x4 oA[8] = {}, oB[8] = {};
  float mA[4], slA[4], mB[4], slB[4];
#pragma unroll
  for (int q = 0; q < 4; ++q) { mA[q] = -1e30f; slA[q] = 0.f; mB[q] = -1e30f; slB[q] = 0.f; }

  auto STAGE = [&](int t) {
    const int kv0 = t * 64;
#pragma unroll
    for (int i = 0; i < 4; ++i) {
      const int seg = w * 4 + i;
      {  // K: 64 rows x 128 cols; seg = 4 rows of 256B
        const int lr = seg * 4 + (lane >> 4);
        const int cs = (lane & 15) ^ (lr & 7);
        gll16(kb + ((long)h * T + kv0 + lr) * D + cs * 8,
              (bf16*)&Kl[0][0] + seg * 512);
      }
      {  // V: 128 rows x 64 cols; seg = 8 rows of 128B
        const int lr = seg * 8 + (lane >> 3);
        const int cs = (lane & 7) ^ (lr & 7);
        gll16(vt + ((long)h * D + lr) * T + kv0 + cs * 8,
              (bf16*)&Vl[0][0] + seg * 512);
      }
    }
  };

  // softmax update + swizzled P write (raw-score domain, scale folded into kC1)
  auto smup = [&](f32x4 (&st4)[4], float* m, float* sl, f32x4 (&o)[8],
                  bf16* Pb, bool diag, int qt, int tt) {
    if (diag) {
      const int qgl = qt * 64 + w * 16 + 4 * g;
#pragma unroll
      for (int stt = 0; stt < 4; ++stt)
#pragma unroll
        for (int q = 0; q < 4; ++q)
          if (tt * 64 + stt * 16 + r > qgl + q) st4[stt][q] = -1e30f;
    }
    float mx[4];
#pragma unroll
    for (int q = 0; q < 4; ++q)
      mx[q] = fmaxf(fmaxf(st4[0][q], st4[1][q]), fmaxf(st4[2][q], st4[3][q]));
    const float dd = fmaxf(fmaxf(mx[0] - m[0], mx[1] - m[1]),
                           fmaxf(mx[2] - m[2], mx[3] - m[3]));
    if (__any(dd > kTHR)) {
#pragma unroll
      for (int off = 1; off < 16; off <<= 1)
#pragma unroll
        for (int q = 0; q < 4; ++q) mx[q] = fmaxf(mx[q], __shfl_xor(mx[q], off));
#pragma unroll
      for (int q = 0; q < 4; ++q) {
        const float nm = fmaxf(m[q], mx[q]);
        const float al = exp2f((m[q] - nm) * kC1);
        m[q] = nm;
        sl[q] *= al;
#pragma unroll
        for (int nn = 0; nn < 8; ++nn) o[nn][q] *= al;
      }
    }
    // explicit subtract (NOT fma with precomputed m*kC1): masked rows have
    // st=m=-1e30; fma residue can reach +-2^74 -> exp2 -> inf -> NaN in merge.
#pragma unroll
    for (int stt = 0; stt < 4; ++stt)
#pragma unroll
      for (int q = 0; q < 4; ++q)
        st4[stt][q] = exp2f((st4[stt][q] - m[q]) * kC1);
#pragma unroll
    for (int q = 0; q < 4; ++q)
      sl[q] += (st4[0][q] + st4[1][q]) + (st4[2][q] + st4[3][q]);
#pragma unroll
    for (int stt = 0; stt < 4; ++stt)
#pragma unroll
      for (int q = 0; q < 4; ++q) {
        const int rw = 4 * g + q;
        Pb[rw * 64 + ((stt * 16 + r) ^ ((rw & 7) << 3))] = (bf16)st4[stt][q];
      }
  };

  STAGE(ts);
  __syncthreads();
  for (int tt = ts; tt < te; ++tt) {
    const bf16* Kb = (const bf16*)&Kl[0][0];
    const bf16* Vb = (const bf16*)&Vl[0][0];
    bf16* PbA = &Pl[w][0][0][0];
    bf16* PbB = &Pl[w][1][0][0];
    const bool doA = (tt <= qtA);  // block-uniform
    f32x4 stA[4], stB[4];
    __builtin_amdgcn_s_setprio(1);
    if (doA) {
#pragma unroll
      for (int stt = 0; stt < 4; ++stt) {
        f32x4 a1 = {}, a2 = {};
        const int lrk = stt * 16 + r;
#pragma unroll
        for (int kk = 0; kk < 4; ++kk) {
          const bf16x8 kf = *(const bf16x8*)(Kb + lrk * 128 + (((kk * 4 + g) ^ (lrk & 7)) * 8));
          a1 = __builtin_amdgcn_mfma_f32_16x16x32_bf16(qfA[kk], kf, a1, 0, 0, 0);
          a2 = __builtin_amdgcn_mfma_f32_16x16x32_bf16(qfB[kk], kf, a2, 0, 0, 0);
        }
        stA[stt] = a1; stB[stt] = a2;
      }
    } else {
#pragma unroll
      for (int stt = 0; stt < 4; ++stt) {
        f32x4 a2 = {};
        const int lrk = stt * 16 + r;
#pragma unroll
        for (int kk = 0; kk < 4; ++kk) {
          const bf16x8 kf = *(const bf16x8*)(Kb + lrk * 128 + (((kk * 4 + g) ^ (lrk & 7)) * 8));
          a2 = __builtin_amdgcn_mfma_f32_16x16x32_bf16(qfB[kk], kf, a2, 0, 0, 0);
        }
        stB[stt] = a2;
      }
    }
    __builtin_amdgcn_s_setprio(0);
    if (doA) smup(stA, mA, slA, oA, PbA, tt == qtA, qtA, tt);
    smup(stB, mB, slB, oB, PbB, tt == qtB, qtB, tt);
    bf16x8 pfA[2], pfB[2];
#pragma unroll
    for (int kk = 0; kk < 2; ++kk) {
      pfA[kk] = *(const bf16x8*)(PbA + r * 64 + (((kk * 4 + g) ^ (r & 7)) * 8));
      pfB[kk] = *(const bf16x8*)(PbB + r * 64 + (((kk * 4 + g) ^ (r & 7)) * 8));
    }
    __builtin_amdgcn_s_setprio(1);
    if (doA) {
#pragma unroll
      for (int nn = 0; nn < 8; ++nn) {
        const int d = nn * 16 + r;
#pragma unroll
        for (int kk = 0; kk < 2; ++kk) {
          const bf16x8 vf = *(const bf16x8*)(Vb + d * 64 + (((kk * 4 + g) ^ (d & 7)) * 8));
          oA[nn] = __builtin_amdgcn_mfma_f32_16x16x32_bf16(pfA[kk], vf, oA[nn], 0, 0, 0);
          oB[nn] = __builtin_amdgcn_mfma_f32_16x16x32_bf16(pfB[kk], vf, oB[nn], 0, 0, 0);
        }
      }
    } else {
#pragma unroll
      for (int nn = 0; nn < 8; ++nn) {
        const int d = nn * 16 + r;
#pragma unroll
        for (int kk = 0; kk < 2; ++kk) {
          const bf16x8 vf = *(const bf16x8*)(Vb + d * 64 + (((kk * 4 + g) ^ (d & 7)) * 8));
          oB[nn] = __builtin_amdgcn_mfma_f32_16x16x32_bf16(pfB[kk], vf, oB[nn], 0, 0, 0);
        }
      }
    }
    __builtin_amdgcn_s_setprio(0);
    if (tt + 1 < te) {
      __syncthreads();
      STAGE(tt + 1);
      __syncthreads();
    }
  }
#pragma unroll
  for (int off = 1; off < 16; off <<= 1)
#pragma unroll
    for (int q = 0; q < 4; ++q) {
      slA[q] += __shfl_xor(slA[q], off);
      slB[q] += __shfl_xor(slB[q], off);
    }
  const int row0 = w * 16 + 4 * g;
  if (s < 4) {  // single chunk: final output directly
#pragma unroll
    for (int nn = 0; nn < 8; ++nn)
#pragma unroll
      for (int q = 0; q < 4; ++q) {
        yb[(long)(qtA * 64 + row0 + q) * DIM + h * D + nn * 16 + r] = (bf16)(oA[nn][q] / slA[q]);
        yb[(long)(qtB * 64 + row0 + q) * DIM + h * D + nn * 16 + r] = (bf16)(oB[nn][q] / slB[q]);
      }
  } else {
    const long partA = (long)h * PPH + (pre_qt(qtA) - 8) + ci;
    const long partB = (long)h * PPH + (pre_qt(qtB) - 8) + ci;
    bf16* poA = po + partA * 8192;
    bf16* poB = po + partB * 8192;
#pragma unroll
    for (int nn = 0; nn < 8; ++nn)
#pragma unroll
      for (int q = 0; q < 4; ++q) {
        poA[(row0 + q) * 128 + nn * 16 + r] = (bf16)oA[nn][q];
        poB[(row0 + q) * 128 + nn * 16 + r] = (bf16)oB[nn][q];
      }
    if (r == 0) {
#pragma unroll
      for (int q = 0; q < 4; ++q) {
        pm[partA * 64 + row0 + q] = mA[q];
        ps[partA * 64 + row0 + q] = slA[q];
        pm[partB * 64 + row0 + q] = mB[q];
        ps[partB * 64 + row0 + q] = slB[q];
      }
    }
  }
}

// Merge 2..8 KV-chunk partials per (qt>=8, h) -> yb. Scratch-free (3 scalar passes).
__global__ __launch_bounds__(256) void attn_reduce(const bf16* __restrict__ po,
                                                   const float* __restrict__ pm,
                                                   const float* __restrict__ ps,
                                                   bf16* __restrict__ yb) {
  const int qt = 8 + blockIdx.x, h = blockIdx.y;
  const int tid = threadIdx.x;
  const int row = tid >> 2, seg = (tid & 3) * 32;
  const int nch = (qt >> 3) + 1;
  const long base = (long)h * PPH + pre_qt(qt) - 8;
  float mm = -1e30f;
  for (int ci = 0; ci < nch; ++ci) mm = fmaxf(mm, pm[(base + ci) * 64 + row]);
  float den = 0.f;
  for (int ci = 0; ci < nch; ++ci)
    den += ps[(base + ci) * 64 + row] * exp2f((pm[(base + ci) * 64 + row] - mm) * kC1);
  const float inv = 1.f / den;
  float acc[32] = {};
  for (int ci = 0; ci < nch; ++ci) {
    const float wq = exp2f((pm[(base + ci) * 64 + row] - mm) * kC1) * inv;
    const bf16* src = po + (base + ci) * 8192 + row * 128 + seg;
#pragma unroll
    for (int j = 0; j < 32; j += 8) {
      const bf16x8 v = *(const bf16x8*)(src + j);
#pragma unroll
      for (int u = 0; u < 8; ++u) acc[j + u] += wq * (float)v[u];
    }
  }
  bf16 outv[32];
#pragma unroll
  for (int j = 0; j < 32; ++j) outv[j] = (bf16)acc[j];
  bf16* dst = yb + (long)(qt * 64 + row) * DIM + h * D + seg;
#pragma unroll
  for (int cc = 0; cc < 4; ++cc)
    *(int4*)(dst + cc * 8) = *(const int4*)&outv[cc * 8];
}

extern "C" void kernel_launch(void* const* d_in, const int* in_sizes, int n_in,
                              void* d_out, int out_size, void* d_ws, size_t ws_size,
                              hipStream_t stream) {
  const float* x     = (const float*)d_in[0];
  const float* ve    = (const float*)d_in[1];
  const float* qkv_w = (const float*)d_in[2];
  const float* lam   = (const float*)d_in[3];
  const float* cproj = (const float*)d_in[4];
  float* out = (float*)d_out;

  // Region A (consumed before attn; aliased by po/pm/ps):
  bf16* qkv = (bf16*)d_ws;                 // T*N3            18.87MB
  bf16* xb  = qkv + (long)T * N3;          // T*DIM            6.29MB
  bf16* wb  = xb + (long)T * DIM;          // N3*DIM           3.54MB
  // Region B (live across attn):
  bf16* cb  = wb + (long)N3 * DIM;         // DIM*DIM
  bf16* qb  = cb + (long)DIM * DIM;        // H*T*D
  bf16* kb  = qb + (long)H * T * D;
  bf16* vt  = kb + (long)H * T * D;        // (h, d, t)
  bf16* yb  = vt + (long)H * T * D;        // T*DIM
  float2* tab = (float2*)(yb + (long)T * DIM);  // T*32 float2
  // Partials alias region A (dead by attn): 280*6 entries = 28.4MB <= 28.7MB
  bf16* po  = (bf16*)d_ws;                            // PPH*H * 8192 bf16
  float* pm = (float*)(po + (long)PPH * H * 8192);    // PPH*H * 64
  float* ps = pm + (long)PPH * H * 64;                // PPH*H * 64

  const int NBX = T * DIM / 2048, NBW = N3 * DIM / 2048, NBC = DIM * DIM / 2048;
  prep<<<dim3(NBX + NBW + NBC + T * 32 / 256), 256, 0, stream>>>(x, qkv_w, cproj, xb, wb, cb, tab);

  gemm_bt<bf16><<<dim3(N3 / 128, T / 128), 256, 0, stream>>>(xb, wb, qkv, T, N3, DIM);
  qkv_post<<<dim3(T * H / 4), 256, 0, stream>>>(qkv, tab, qb, kb);
  v_trans<<<dim3(T / 64, H), 256, 0, stream>>>(qkv, ve, lam, vt);
  attn<<<dim3(144 * H), 256, 0, stream>>>(qb, kb, vt, po, pm, ps, yb);
  attn_reduce<<<dim3(56, H), 256, 0, stream>>>(po, pm, ps, yb);
  gemm_bt<float><<<dim3(DIM / 128, T / 128), 256, 0, stream>>>(yb, cb, out, T, DIM, DIM);
}

// Round 9
// 154.231 us; speedup vs baseline: 2.5408x; 2.5408x over previous
//
#include <hip/hip_runtime.h>
#include <hip/hip_bf16.h>

using bf16 = __hip_bfloat16;
typedef __attribute__((ext_vector_type(8))) __bf16 bf16x8;
typedef __attribute__((ext_vector_type(4))) float f32x4;

static constexpr int T = 4096, DIM = 768, H = 6, D = 128, N3 = 2304;
static constexpr int PPH = 280;                    // stored partials per head (qt>=8)
static constexpr float kEps = 1.1920929e-07f;
static constexpr float kC1 = 0.12f * 1.44269504f;  // kScale * log2(e)
static constexpr float kTHR = 66.6f;               // raw-domain defer threshold (~e^8 P bound)

__device__ __forceinline__ void gll16(const bf16* g, bf16* l) {
  __builtin_amdgcn_global_load_lds((const __attribute__((address_space(1))) void*)g,
                                   (__attribute__((address_space(3))) void*)l, 16, 0, 0);
}

// sum_{q'<qt} ((q'>>3)+1)
__device__ __forceinline__ int pre_qt(int qt) {
  const int k = qt >> 3, rr = qt & 7;
  return qt + 4 * k * (k - 1) + rr * k;
}

// fused fp32->bf16 converts (x, qkv_w, cproj) + rotary table build
__global__ __launch_bounds__(256) void prep(const float* __restrict__ x,
                                            const float* __restrict__ qkv_w,
                                            const float* __restrict__ cproj,
                                            bf16* __restrict__ xb, bf16* __restrict__ wb,
                                            bf16* __restrict__ cb, float2* __restrict__ tab) {
  const int NBX = T * DIM / 2048, NBW = N3 * DIM / 2048, NBC = DIM * DIM / 2048;
  int b = blockIdx.x;
  const int tid = threadIdx.x;
  if (b < NBX + NBW + NBC) {
    const float* in;
    bf16* out;
    if (b < NBX) { in = x; out = xb; }
    else if (b < NBX + NBW) { in = qkv_w; out = wb; b -= NBX; }
    else { in = cproj; out = cb; b -= NBX + NBW; }
    const int i = (b * 256 + tid) * 8;
    const float4 a = *(const float4*)(in + i);
    const float4 c = *(const float4*)(in + i + 4);
    bf16 t[8] = {(bf16)a.x, (bf16)a.y, (bf16)a.z, (bf16)a.w,
                 (bf16)c.x, (bf16)c.y, (bf16)c.z, (bf16)c.w};
    *(int4*)(out + i) = *(const int4*)t;
  } else {
    b -= NBX + NBW + NBC;
    const int i = b * 256 + tid;  // T*32 total
    const int t = i >> 5, j = i & 31;
    const float af = exp2f(-10.f * (float)j * (1.f / 31.f));
    float s, c;
    sincosf((float)t * af, &s, &c);
    tab[i] = make_float2(c, s);
  }
}

// C(MxN) = A(MxK) * B(NxK)^T, A/B row-major bf16, C row-major CT.
template <typename CT>
__global__ __launch_bounds__(256) void gemm_bt(const bf16* __restrict__ A,
                                               const bf16* __restrict__ B,
                                               CT* __restrict__ C,
                                               int M, int N, int K) {
  __shared__ bf16 lA[128][64];
  __shared__ bf16 lB[128][64];
  const int tid = threadIdx.x, lane = tid & 63, wid = tid >> 6;
  const int brow = blockIdx.y * 128, bcol = blockIdx.x * 128;
  const int wm = (wid >> 1) * 64, wn = (wid & 1) * 64;
  const int r = lane & 15, g = lane >> 4;
  f32x4 acc[4][4] = {};
  const int srow = wid * 32 + (lane >> 3);
  const int scol = (lane & 7) * 8;
  const bf16* gA = A + (long)(brow + srow) * K + scol;
  const bf16* gB = B + (long)(bcol + srow) * K + scol;
  for (int k0 = 0; k0 < K; k0 += 64) {
    __syncthreads();
#pragma unroll
    for (int i = 0; i < 4; ++i) {
      gll16(gA + (long)i * 8 * K + k0, &lA[wid * 32 + i * 8][0]);
      gll16(gB + (long)i * 8 * K + k0, &lB[wid * 32 + i * 8][0]);
    }
    __syncthreads();
#pragma unroll
    for (int kk = 0; kk < 2; ++kk) {
      bf16x8 af[4], bfr[4];
#pragma unroll
      for (int m = 0; m < 4; ++m)
        af[m] = *(const bf16x8*)&lA[wm + m * 16 + r][kk * 32 + g * 8];
#pragma unroll
      for (int n = 0; n < 4; ++n)
        bfr[n] = *(const bf16x8*)&lB[wn + n * 16 + r][kk * 32 + g * 8];
#pragma unroll
      for (int m = 0; m < 4; ++m)
#pragma unroll
        for (int n = 0; n < 4; ++n)
          acc[m][n] = __builtin_amdgcn_mfma_f32_16x16x32_bf16(af[m], bfr[n], acc[m][n], 0, 0, 0);
    }
  }
  const int crow = brow + wm + g * 4;
  const int ccol = bcol + wn + r;
#pragma unroll
  for (int m = 0; m < 4; ++m)
#pragma unroll
    for (int n = 0; n < 4; ++n)
#pragma unroll
      for (int q = 0; q < 4; ++q)
        C[(long)(crow + m * 16 + q) * N + ccol + n * 16] = (CT)acc[m][n][q];
}

// RMS-norm + rotary for q,k only (table-driven). One wave per (t,h). Writes (h,t,d).
__global__ __launch_bounds__(256) void qkv_post(const bf16* __restrict__ qkv,
                                                const float2* __restrict__ tab,
                                                bf16* __restrict__ qb,
                                                bf16* __restrict__ kb) {
  const int idx = blockIdx.x * 4 + (threadIdx.x >> 6);
  const int lane = threadIdx.x & 63;
  const int t = idx / H, h = idx % H;
  const bf16* row = qkv + (long)t * N3 + h * D;
  float q1 = __bfloat162float(row[lane]);
  float q2 = __bfloat162float(row[lane + 64]);
  float k1 = __bfloat162float(row[768 + lane]);
  float k2 = __bfloat162float(row[768 + lane + 64]);
  float qs = q1 * q1 + q2 * q2, ks = k1 * k1 + k2 * k2;
#pragma unroll
  for (int off = 32; off; off >>= 1) {
    qs += __shfl_xor(qs, off);
    ks += __shfl_xor(ks, off);
  }
  const float qsc = rsqrtf(qs * (1.f / 128.f) + kEps);
  const float ksc = rsqrtf(ks * (1.f / 128.f) + kEps);
  q1 *= qsc; q2 *= qsc; k1 *= ksc; k2 *= ksc;
  float c = 1.f, s = 0.f;
  if (lane < 32) {
    const float2 cs = tab[t * 32 + lane];
    c = cs.x; s = cs.y;
  }
  const float nq1 = q1 * c + q2 * s, nq2 = q2 * c - q1 * s;
  const float nk1 = k1 * c + k2 * s, nk2 = k2 * c - k1 * s;
  bf16* qo = qb + ((long)h * T + t) * D;
  bf16* ko = kb + ((long)h * T + t) * D;
  qo[lane] = (bf16)nq1; qo[lane + 64] = (bf16)nq2;
  ko[lane] = (bf16)nk1; ko[lane + 64] = (bf16)nk2;
}

// v = l0*v + l1*ve, transposed to (h, d, t) with coalesced 64B stores.
__global__ __launch_bounds__(256) void v_trans(const bf16* __restrict__ qkv,
                                               const float* __restrict__ ve,
                                               const float* __restrict__ lam,
                                               bf16* __restrict__ vt) {
  __shared__ bf16 tile[64][129];
  const int t0 = blockIdx.x * 64, h = blockIdx.y;
  const int tid = threadIdx.x;
  const float l0 = lam[0], l1 = lam[1];
  const int row = tid >> 2;
  const int seg = (tid & 3) * 32;
  const bf16* src = qkv + (long)(t0 + row) * N3 + 1536 + h * D + seg;
  const float* vs = ve + (long)(t0 + row) * DIM + h * D + seg;
#pragma unroll
  for (int j = 0; j < 32; j += 8) {
    bf16x8 a = *(const bf16x8*)(src + j);
    const float4 e0 = *(const float4*)(vs + j);
    const float4 e1 = *(const float4*)(vs + j + 4);
    const float ef[8] = {e0.x, e0.y, e0.z, e0.w, e1.x, e1.y, e1.z, e1.w};
#pragma unroll
    for (int u = 0; u < 8; ++u)
      tile[row][seg + j + u] = (bf16)(l0 * (float)a[u] + l1 * ef[u]);
  }
  __syncthreads();
  const int d = tid >> 1, half = tid & 1;
  bf16 outr[32];
#pragma unroll
  for (int j = 0; j < 32; ++j) outr[j] = tile[half * 32 + j][d];
  bf16* dst = vt + ((long)h * D + d) * T + t0 + half * 32;
#pragma unroll
  for (int c = 0; c < 4; ++c)
    *(int4*)(dst + c * 8) = *(const int4*)&outr[c * 8];
}

// Flash-style causal attention. 512-thread block = 128-row q-supertile (8 waves,
// waves 0-3 -> q-tile 2s, waves 4-7 -> q-tile 2s+1) sharing one staged K/V tile.
// KVBLK=64 single-buffered, chunks of 8 tiles, 48KB LDS. Per-wave state == R7
// (no spill: __launch_bounds__(512,4) caps at 128 regs, R7 used 64).
__global__ __launch_bounds__(512, 4) void attn(const bf16* __restrict__ qb,
                                               const bf16* __restrict__ kb,
                                               const bf16* __restrict__ vt,
                                               bf16* __restrict__ po,
                                               float* __restrict__ pm,
                                               float* __restrict__ ps,
                                               bf16* __restrict__ yb) {
  __shared__ bf16 Kl[64][128];
  __shared__ bf16 Vl[128][64];
  __shared__ bf16 Pl[8][16][64];
  const int bid = blockIdx.x;
  const int h = bid % H;
  const int fi = bid / H;
  int s = 31, ci = 0, acc0 = 0;          // heavy-first band decode
  for (int ss = 31; ss >= 0; --ss) {
    const int n = (ss >> 2) + 1;
    if (fi < acc0 + n) { s = ss; ci = fi - acc0; break; }
    acc0 += n;
  }
  const int tid = threadIdx.x, lane = tid & 63, w = tid >> 6;  // w in 0..7
  const int r = lane & 15, g = lane >> 4;
  const int qt = 2 * s + (w >> 2);       // this wave's q-tile
  const int wrow = (w & 3) * 16;         // row offset within q-tile
  const int ts = ci * 8;
  const int te = min(ts + 8, 2 * s + 2);

  bf16x8 qf[4];
#pragma unroll
  for (int kk = 0; kk < 4; ++kk)
    qf[kk] = *(const bf16x8*)(qb + ((long)h * T + qt * 64 + wrow + r) * D + kk * 32 + g * 8);
  f32x4 o[8] = {};
  float m[4], sl[4];
#pragma unroll
  for (int q = 0; q < 4; ++q) { m[q] = -1e30f; sl[q] = 0.f; }

  auto STAGE = [&](int t) {
    const int kv0 = t * 64;
#pragma unroll
    for (int i = 0; i < 2; ++i) {
      const int seg = w * 2 + i;         // 16 segs of 1KB each for K and V
      {  // K: 64 rows x 128 cols; seg = 4 rows of 256B
        const int lr = seg * 4 + (lane >> 4);
        const int cs = (lane & 15) ^ (lr & 7);
        gll16(kb + ((long)h * T + kv0 + lr) * D + cs * 8,
              (bf16*)&Kl[0][0] + seg * 512);
      }
      {  // V: 128 rows x 64 cols; seg = 8 rows of 128B
        const int lr = seg * 8 + (lane >> 3);
        const int cs = (lane & 7) ^ (lr & 7);
        gll16(vt + ((long)h * D + lr) * T + kv0 + cs * 8,
              (bf16*)&Vl[0][0] + seg * 512);
      }
    }
  };

  STAGE(ts);
  __syncthreads();
  for (int tt = ts; tt < te; ++tt) {
    const bool act = (tt <= qt);         // wave-uniform; A-waves skip last tile
    if (act) {
      const bf16* Kb = (const bf16*)&Kl[0][0];
      const bf16* Vb = (const bf16*)&Vl[0][0];
      bf16* Pb = &Pl[w][0][0];
      f32x4 st4[4];
      __builtin_amdgcn_s_setprio(1);
#pragma unroll
      for (int stt = 0; stt < 4; ++stt) {
        f32x4 a = {};
        const int lrk = stt * 16 + r;
#pragma unroll
        for (int kk = 0; kk < 4; ++kk) {
          const bf16x8 kf = *(const bf16x8*)(Kb + lrk * 128 + (((kk * 4 + g) ^ (lrk & 7)) * 8));
          a = __builtin_amdgcn_mfma_f32_16x16x32_bf16(qf[kk], kf, a, 0, 0, 0);
        }
        st4[stt] = a;
      }
      __builtin_amdgcn_s_setprio(0);
      if (tt == qt) {  // diagonal tile: causal mask (raw domain)
        const int qgl = qt * 64 + wrow + 4 * g;
#pragma unroll
        for (int stt = 0; stt < 4; ++stt)
#pragma unroll
          for (int q = 0; q < 4; ++q)
            if (tt * 64 + stt * 16 + r > qgl + q) st4[stt][q] = -1e30f;
      }
      float mx[4];
#pragma unroll
      for (int q = 0; q < 4; ++q)
        mx[q] = fmaxf(fmaxf(st4[0][q], st4[1][q]), fmaxf(st4[2][q], st4[3][q]));
      const float dd = fmaxf(fmaxf(mx[0] - m[0], mx[1] - m[1]),
                             fmaxf(mx[2] - m[2], mx[3] - m[3]));
      if (__any(dd > kTHR)) {  // rare: full max-reduce + rescale
#pragma unroll
        for (int off = 1; off < 16; off <<= 1)
#pragma unroll
          for (int q = 0; q < 4; ++q) mx[q] = fmaxf(mx[q], __shfl_xor(mx[q], off));
#pragma unroll
        for (int q = 0; q < 4; ++q) {
          const float nm = fmaxf(m[q], mx[q]);
          const float al = exp2f((m[q] - nm) * kC1);
          m[q] = nm;
          sl[q] *= al;
#pragma unroll
          for (int nn = 0; nn < 8; ++nn) o[nn][q] *= al;
        }
      }
      // P = exp2((st - m)*kC1). Explicit subtract (NOT fma with precomputed
      // m*kC1): masked rows have st=m=-1e30; fma residue can reach +-2^74
      // -> exp2 -> inf -> 0*inf = NaN in the merge.
#pragma unroll
      for (int stt = 0; stt < 4; ++stt)
#pragma unroll
        for (int q = 0; q < 4; ++q)
          st4[stt][q] = exp2f((st4[stt][q] - m[q]) * kC1);
#pragma unroll
      for (int q = 0; q < 4; ++q)
        sl[q] += (st4[0][q] + st4[1][q]) + (st4[2][q] + st4[3][q]);
#pragma unroll
      for (int stt = 0; stt < 4; ++stt)
#pragma unroll
        for (int q = 0; q < 4; ++q) {
          const int rw = 4 * g + q;
          Pb[rw * 64 + ((stt * 16 + r) ^ ((rw & 7) << 3))] = (bf16)st4[stt][q];
        }
      bf16x8 pf[2];
#pragma unroll
      for (int kk = 0; kk < 2; ++kk)
        pf[kk] = *(const bf16x8*)(Pb + r * 64 + (((kk * 4 + g) ^ (r & 7)) * 8));
      __builtin_amdgcn_s_setprio(1);
#pragma unroll
      for (int nn = 0; nn < 8; ++nn) {
        const int d = nn * 16 + r;
#pragma unroll
        for (int kk = 0; kk < 2; ++kk) {
          const bf16x8 vf = *(const bf16x8*)(Vb + d * 64 + (((kk * 4 + g) ^ (d & 7)) * 8));
          o[nn] = __builtin_amdgcn_mfma_f32_16x16x32_bf16(pf[kk], vf, o[nn], 0, 0, 0);
        }
      }
      __builtin_amdgcn_s_setprio(0);
    }
    if (tt + 1 < te) {
      __syncthreads();   // all waves done reading K/V before overwrite
      STAGE(tt + 1);
      __syncthreads();   // staged data visible
    }
  }
  // epilogue: reduce distributed s across the 16-lane row group
#pragma unroll
  for (int off = 1; off < 16; off <<= 1)
#pragma unroll
    for (int q = 0; q < 4; ++q) sl[q] += __shfl_xor(sl[q], off);
  const int row0 = wrow + 4 * g;         // row within this wave's q-tile
  if (s < 4) {  // single chunk: final output directly
#pragma unroll
    for (int nn = 0; nn < 8; ++nn)
#pragma unroll
      for (int q = 0; q < 4; ++q)
        yb[(long)(qt * 64 + row0 + q) * DIM + h * D + nn * 16 + r] = (bf16)(o[nn][q] / sl[q]);
  } else {
    const long part = (long)h * PPH + (pre_qt(qt) - 8) + ci;
    bf16* pob = po + part * 8192;
#pragma unroll
    for (int nn = 0; nn < 8; ++nn)
#pragma unroll
      for (int q = 0; q < 4; ++q)
        pob[(row0 + q) * 128 + nn * 16 + r] = (bf16)o[nn][q];
    if (r == 0) {
#pragma unroll
      for (int q = 0; q < 4; ++q) {
        pm[part * 64 + row0 + q] = m[q];
        ps[part * 64 + row0 + q] = sl[q];
      }
    }
  }
}

// Merge 2..8 KV-chunk partials per (qt>=8, h) -> yb. Scratch-free (3 scalar passes).
__global__ __launch_bounds__(256) void attn_reduce(const bf16* __restrict__ po,
                                                   const float* __restrict__ pm,
                                                   const float* __restrict__ ps,
                                                   bf16* __restrict__ yb) {
  const int qt = 8 + blockIdx.x, h = blockIdx.y;
  const int tid = threadIdx.x;
  const int row = tid >> 2, seg = (tid & 3) * 32;
  const int nch = (qt >> 3) + 1;
  const long base = (long)h * PPH + pre_qt(qt) - 8;
  float mm = -1e30f;
  for (int ci = 0; ci < nch; ++ci) mm = fmaxf(mm, pm[(base + ci) * 64 + row]);
  float den = 0.f;
  for (int ci = 0; ci < nch; ++ci)
    den += ps[(base + ci) * 64 + row] * exp2f((pm[(base + ci) * 64 + row] - mm) * kC1);
  const float inv = 1.f / den;
  float acc[32] = {};
  for (int ci = 0; ci < nch; ++ci) {
    const float wq = exp2f((pm[(base + ci) * 64 + row] - mm) * kC1) * inv;
    const bf16* src = po + (base + ci) * 8192 + row * 128 + seg;
#pragma unroll
    for (int j = 0; j < 32; j += 8) {
      const bf16x8 v = *(const bf16x8*)(src + j);
#pragma unroll
      for (int u = 0; u < 8; ++u) acc[j + u] += wq * (float)v[u];
    }
  }
  bf16 outv[32];
#pragma unroll
  for (int j = 0; j < 32; ++j) outv[j] = (bf16)acc[j];
  bf16* dst = yb + (long)(qt * 64 + row) * DIM + h * D + seg;
#pragma unroll
  for (int cc = 0; cc < 4; ++cc)
    *(int4*)(dst + cc * 8) = *(const int4*)&outv[cc * 8];
}

extern "C" void kernel_launch(void* const* d_in, const int* in_sizes, int n_in,
                              void* d_out, int out_size, void* d_ws, size_t ws_size,
                              hipStream_t stream) {
  const float* x     = (const float*)d_in[0];
  const float* ve    = (const float*)d_in[1];
  const float* qkv_w = (const float*)d_in[2];
  const float* lam   = (const float*)d_in[3];
  const float* cproj = (const float*)d_in[4];
  float* out = (float*)d_out;

  // Region A (consumed before attn; aliased by po/pm/ps):
  bf16* qkv = (bf16*)d_ws;                 // T*N3
  bf16* xb  = qkv + (long)T * N3;          // T*DIM
  bf16* wb  = xb + (long)T * DIM;          // N3*DIM
  // Region B (live across attn):
  bf16* cb  = wb + (long)N3 * DIM;         // DIM*DIM
  bf16* qb  = cb + (long)DIM * DIM;        // H*T*D
  bf16* kb  = qb + (long)H * T * D;
  bf16* vt  = kb + (long)H * T * D;        // (h, d, t)
  bf16* yb  = vt + (long)H * T * D;        // T*DIM
  float2* tab = (float2*)(yb + (long)T * DIM);  // T*32 float2
  // Partials alias region A (dead by attn): 280*6 entries = 28.4MB <= 28.7MB
  bf16* po  = (bf16*)d_ws;                            // PPH*H * 8192 bf16
  float* pm = (float*)(po + (long)PPH * H * 8192);    // PPH*H * 64
  float* ps = pm + (long)PPH * H * 64;                // PPH*H * 64

  const int NBX = T * DIM / 2048, NBW = N3 * DIM / 2048, NBC = DIM * DIM / 2048;
  prep<<<dim3(NBX + NBW + NBC + T * 32 / 256), 256, 0, stream>>>(x, qkv_w, cproj, xb, wb, cb, tab);

  gemm_bt<bf16><<<dim3(N3 / 128, T / 128), 256, 0, stream>>>(xb, wb, qkv, T, N3, DIM);
  qkv_post<<<dim3(T * H / 4), 256, 0, stream>>>(qkv, tab, qb, kb);
  v_trans<<<dim3(T / 64, H), 256, 0, stream>>>(qkv, ve, lam, vt);
  attn<<<dim3(144 * H), 512, 0, stream>>>(qb, kb, vt, po, pm, ps, yb);
  attn_reduce<<<dim3(56, H), 256, 0, stream>>>(po, pm, ps, yb);
  gemm_bt<float><<<dim3(DIM / 128, T / 128), 256, 0, stream>>>(yb, cb, out, T, DIM, DIM);
}